// Round 2
// baseline (5730.215 us; speedup 1.0000x reference)
//
#include <hip/hip_runtime.h>
#include <cstdint>
#include <cstddef>

// ---------------- config ----------------
#define BB 16
#define SS 512
#define DD 768
#define HH 12
#define FF 3072
#define LL 12
#define DHD 64
#define MM (BB*SS)   // 8192 rows

typedef __attribute__((ext_vector_type(8))) short bf16x8;
typedef __attribute__((ext_vector_type(4))) float f32x4;

__device__ __forceinline__ ushort f2bf(float f) {
  union { float f; uint32_t u; } x; x.f = f;
  uint32_t r = x.u + 0x7FFFu + ((x.u >> 16) & 1u);
  return (ushort)(r >> 16);
}

// ================= embedding + LayerNorm =================
__global__ __launch_bounds__(256)
void embed_ln_kernel(const int* __restrict__ ids, const float* __restrict__ wemb,
                     const float* __restrict__ pemb, const float* __restrict__ g,
                     const float* __restrict__ bt, float* __restrict__ hf,
                     ushort* __restrict__ hb)
{
  const int row = blockIdx.x;
  const int s = row & (SS - 1);
  const int id = ids[row];
  const float* wp = wemb + (size_t)id * DD;
  const float* pp = pemb + (size_t)s * DD;
  const int tid = threadIdx.x;
  float v[3]; float sum = 0.f, sq = 0.f;
#pragma unroll
  for (int j = 0; j < 3; ++j) {
    int e = tid + j * 256;
    v[j] = wp[e] + pp[e];
    sum += v[j]; sq += v[j] * v[j];
  }
  __shared__ float red[2][4];
#pragma unroll
  for (int off = 32; off >= 1; off >>= 1) { sum += __shfl_xor(sum, off); sq += __shfl_xor(sq, off); }
  const int lane = tid & 63, wid = tid >> 6;
  if (lane == 0) { red[0][wid] = sum; red[1][wid] = sq; }
  __syncthreads();
  sum = red[0][0] + red[0][1] + red[0][2] + red[0][3];
  sq  = red[1][0] + red[1][1] + red[1][2] + red[1][3];
  const float mean = sum * (1.f / DD);
  const float var  = sq  * (1.f / DD) - mean * mean;
  const float rstd = rsqrtf(var + 1e-12f);
  const size_t base = (size_t)row * DD;
#pragma unroll
  for (int j = 0; j < 3; ++j) {
    int e = tid + j * 256;
    float o = (v[j] - mean) * rstd * g[e] + bt[e];
    hf[base + e] = o;
    hb[base + e] = f2bf(o);
  }
}

// ================= residual add + LayerNorm =================
__global__ __launch_bounds__(256)
void add_ln_kernel(const float* __restrict__ res, const float* __restrict__ add,
                   const float* __restrict__ g, const float* __restrict__ bt,
                   float* __restrict__ hf, ushort* __restrict__ hb)
{
  const int row = blockIdx.x;
  const int tid = threadIdx.x;
  const size_t base = (size_t)row * DD;
  float v[3]; float sum = 0.f, sq = 0.f;
#pragma unroll
  for (int j = 0; j < 3; ++j) {
    int e = tid + j * 256;
    v[j] = res[base + e] + add[base + e];
    sum += v[j]; sq += v[j] * v[j];
  }
  __shared__ float red[2][4];
#pragma unroll
  for (int off = 32; off >= 1; off >>= 1) { sum += __shfl_xor(sum, off); sq += __shfl_xor(sq, off); }
  const int lane = tid & 63, wid = tid >> 6;
  if (lane == 0) { red[0][wid] = sum; red[1][wid] = sq; }
  __syncthreads();
  sum = red[0][0] + red[0][1] + red[0][2] + red[0][3];
  sq  = red[1][0] + red[1][1] + red[1][2] + red[1][3];
  const float mean = sum * (1.f / DD);
  const float var  = sq  * (1.f / DD) - mean * mean;
  const float rstd = rsqrtf(var + 1e-12f);
#pragma unroll
  for (int j = 0; j < 3; ++j) {
    int e = tid + j * 256;
    float o = (v[j] - mean) * rstd * g[e] + bt[e];
    hf[base + e] = o;
    hb[base + e] = f2bf(o);
  }
}

// ================= GEMM: C[M,N] = A[M,K](bf16) @ Bw[N,K](f32)^T + bias =================
// EPI 0: bf16 out + bias;  1: f32 out + bias;  2: bf16 out + bias + exact gelu
template<int EPI>
__global__ __launch_bounds__(256, 2)
void gemm_bt(const ushort* __restrict__ A, const float* __restrict__ Bw,
             const float* __restrict__ bias, void* __restrict__ Cout,
             int Ndim, int Kdim)
{
  __shared__ ushort As[2][128][40];
  __shared__ ushort Bs[2][128][40];
  const int tid = threadIdx.x;
  const int bm = blockIdx.x, bn = blockIdx.y;
  const int lane = tid & 63, wid = tid >> 6;
  const int wm = wid >> 1, wn = wid & 1;
  const int fr = lane & 15, fg = lane >> 4;
  const int srow = tid >> 1;
  const int sh = (tid & 1) * 16;

  const ushort* Aptr = A  + (size_t)(bm * 128 + srow) * Kdim + sh;
  const float*  Bptr = Bw + (size_t)(bn * 128 + srow) * Kdim + sh;

  f32x4 acc[4][4];
#pragma unroll
  for (int i = 0; i < 4; ++i)
#pragma unroll
    for (int j = 0; j < 4; ++j) acc[i][j] = f32x4{0.f, 0.f, 0.f, 0.f};

  int4 ar0, ar1; float4 br0, br1, br2, br3;

  auto gload = [&](int kt) {
    const ushort* ap = Aptr + kt * 32;
    ar0 = *(const int4*)ap;
    ar1 = *(const int4*)(ap + 8);
    const float* bp = Bptr + kt * 32;
    br0 = *(const float4*)bp;       br1 = *(const float4*)(bp + 4);
    br2 = *(const float4*)(bp + 8); br3 = *(const float4*)(bp + 12);
  };
  auto sstore = [&](int buf) {
    *(int4*)&As[buf][srow][sh]     = ar0;
    *(int4*)&As[buf][srow][sh + 8] = ar1;
    union { ushort u[8]; int4 v; } p0, p1;
    p0.u[0] = f2bf(br0.x); p0.u[1] = f2bf(br0.y); p0.u[2] = f2bf(br0.z); p0.u[3] = f2bf(br0.w);
    p0.u[4] = f2bf(br1.x); p0.u[5] = f2bf(br1.y); p0.u[6] = f2bf(br1.z); p0.u[7] = f2bf(br1.w);
    p1.u[0] = f2bf(br2.x); p1.u[1] = f2bf(br2.y); p1.u[2] = f2bf(br2.z); p1.u[3] = f2bf(br2.w);
    p1.u[4] = f2bf(br3.x); p1.u[5] = f2bf(br3.y); p1.u[6] = f2bf(br3.z); p1.u[7] = f2bf(br3.w);
    *(int4*)&Bs[buf][srow][sh]     = p0.v;
    *(int4*)&Bs[buf][srow][sh + 8] = p1.v;
  };

  gload(0); sstore(0);
  __syncthreads();
  const int nk = Kdim >> 5;
  int cur = 0;
  for (int kt = 0; kt < nk; ++kt) {
    if (kt + 1 < nk) gload(kt + 1);
    bf16x8 af[4], bfv[4];
#pragma unroll
    for (int i = 0; i < 4; ++i) af[i]  = *(const bf16x8*)&As[cur][wm * 64 + i * 16 + fr][fg * 8];
#pragma unroll
    for (int j = 0; j < 4; ++j) bfv[j] = *(const bf16x8*)&Bs[cur][wn * 64 + j * 16 + fr][fg * 8];
#pragma unroll
    for (int i = 0; i < 4; ++i)
#pragma unroll
      for (int j = 0; j < 4; ++j)
        acc[i][j] = __builtin_amdgcn_mfma_f32_16x16x32_bf16(af[i], bfv[j], acc[i][j], 0, 0, 0);
    if (kt + 1 < nk) sstore(cur ^ 1);
    __syncthreads();
    cur ^= 1;
  }

#pragma unroll
  for (int i = 0; i < 4; ++i) {
    const int row0 = bm * 128 + wm * 64 + i * 16 + fg * 4;
#pragma unroll
    for (int j = 0; j < 4; ++j) {
      const int col = bn * 128 + wn * 64 + j * 16 + fr;
      const float bv = bias[col];
#pragma unroll
      for (int r = 0; r < 4; ++r) {
        float v = acc[i][j][r] + bv;
        if (EPI == 2) v = 0.5f * v * (1.0f + erff(v * 0.70710678118f));
        if (EPI == 1) ((float*)Cout)[(size_t)(row0 + r) * Ndim + col] = v;
        else          ((ushort*)Cout)[(size_t)(row0 + r) * Ndim + col] = f2bf(v);
      }
    }
  }
}

// ================= fused flash attention =================
// grid: (S/64, B*H); block 256 = 4 waves, each wave owns 16 q-rows.
__global__ __launch_bounds__(256, 2)
void attn_kernel(const ushort* __restrict__ qb, const ushort* __restrict__ kb,
                 const ushort* __restrict__ vb, const float* __restrict__ relt,
                 const float* __restrict__ amask, ushort* __restrict__ ctxb)
{
  __shared__ ushort Kt[128][72];
  __shared__ ushort Vt[64][136];
  __shared__ ushort Pl[64][136];

  const int tid = threadIdx.x, lane = tid & 63, w = tid >> 6;
  const int qt = blockIdx.x, bh = blockIdx.y;
  const int b = bh / HH, h = bh % HH;
  const int fr = lane & 15, fg = lane >> 4;

  // Q fragments (A-operand): row = fr within wave's 16 rows
  bf16x8 qf[2];
  {
    const int qrow = qt * 64 + w * 16 + fr;
    const ushort* p = qb + ((size_t)(b * SS + qrow) * DD) + h * DHD + fg * 8;
    qf[0] = *(const bf16x8*)p;
    qf[1] = *(const bf16x8*)(p + 32);
  }

  f32x4 o[4];
  float mrow[4], lrow[4];
#pragma unroll
  for (int r = 0; r < 4; ++r) { mrow[r] = -1e30f; lrow[r] = 0.f; }
#pragma unroll
  for (int d = 0; d < 4; ++d) o[d] = f32x4{0.f, 0.f, 0.f, 0.f};

  const int skr = tid >> 1;           // staging row 0..127
  const int shd = (tid & 1) * 32;     // staging d-half

  for (int kt = 0; kt < 4; ++kt) {
    // ---- issue global loads for K/V tile ----
    const size_t gbase = ((size_t)(b * SS + kt * 128 + skr) * DD) + h * DHD + shd;
    int4 kr0 = *(const int4*)(kb + gbase);
    int4 kr1 = *(const int4*)(kb + gbase + 8);
    int4 kr2 = *(const int4*)(kb + gbase + 16);
    int4 kr3 = *(const int4*)(kb + gbase + 24);
    int4 vr0 = *(const int4*)(vb + gbase);
    int4 vr1 = *(const int4*)(vb + gbase + 8);
    int4 vr2 = *(const int4*)(vb + gbase + 16);
    int4 vr3 = *(const int4*)(vb + gbase + 24);

    __syncthreads();   // previous iteration's LDS reads complete
    *(int4*)&Kt[skr][shd]      = kr0;
    *(int4*)&Kt[skr][shd + 8]  = kr1;
    *(int4*)&Kt[skr][shd + 16] = kr2;
    *(int4*)&Kt[skr][shd + 24] = kr3;
    {
      union { int4 v; ushort u[8]; } t;
      t.v = vr0;
#pragma unroll
      for (int e = 0; e < 8; ++e) Vt[shd + e][skr] = t.u[e];
      t.v = vr1;
#pragma unroll
      for (int e = 0; e < 8; ++e) Vt[shd + 8 + e][skr] = t.u[e];
      t.v = vr2;
#pragma unroll
      for (int e = 0; e < 8; ++e) Vt[shd + 16 + e][skr] = t.u[e];
      t.v = vr3;
#pragma unroll
      for (int e = 0; e < 8; ++e) Vt[shd + 24 + e][skr] = t.u[e];
    }
    __syncthreads();   // staging visible

    // ---- QK^T + score epilogue ----
    float sv[8][4];
#pragma unroll
    for (int kc = 0; kc < 8; ++kc) {
      f32x4 s = f32x4{0.f, 0.f, 0.f, 0.f};
      bf16x8 kf0 = *(const bf16x8*)&Kt[kc * 16 + fr][fg * 8];
      bf16x8 kf1 = *(const bf16x8*)&Kt[kc * 16 + fr][32 + fg * 8];
      s = __builtin_amdgcn_mfma_f32_16x16x32_bf16(qf[0], kf0, s, 0, 0, 0);
      s = __builtin_amdgcn_mfma_f32_16x16x32_bf16(qf[1], kf1, s, 0, 0, 0);
      const int col = kt * 128 + kc * 16 + fr;
      const float am = (1.0f - amask[b * SS + col]) * -10000.0f;
#pragma unroll
      for (int r = 0; r < 4; ++r) {
        const int qg = qt * 64 + w * 16 + fg * 4 + r;
        int rel = col - qg;
        rel = min(128, max(-128, rel)) + 128;
        sv[kc][r] = s[r] * 0.125f + relt[rel * HH + h] + am;
      }
    }

    // ---- online softmax (rows spread across 16-lane groups) ----
    float ef[4];
#pragma unroll
    for (int r = 0; r < 4; ++r) {
      float tmax = sv[0][r];
#pragma unroll
      for (int kc = 1; kc < 8; ++kc) tmax = fmaxf(tmax, sv[kc][r]);
#pragma unroll
      for (int off = 1; off < 16; off <<= 1) tmax = fmaxf(tmax, __shfl_xor(tmax, off));
      const float mnew = fmaxf(mrow[r], tmax);
      ef[r] = __expf(mrow[r] - mnew);
      float psum = 0.f;
      const int prow = w * 16 + fg * 4 + r;
#pragma unroll
      for (int kc = 0; kc < 8; ++kc) {
        float p = __expf(sv[kc][r] - mnew);
        psum += p;
        Pl[prow][kc * 16 + fr] = f2bf(p);
      }
#pragma unroll
      for (int off = 1; off < 16; off <<= 1) psum += __shfl_xor(psum, off);
      lrow[r] = lrow[r] * ef[r] + psum;
      mrow[r] = mnew;
    }
    // per-row rescale of the O accumulator: o[dc][r] is row fg*4+r
#pragma unroll
    for (int dc = 0; dc < 4; ++dc)
#pragma unroll
      for (int r = 0; r < 4; ++r) o[dc][r] *= ef[r];
    __syncthreads();   // P visible

    // ---- PV ----
#pragma unroll
    for (int dc = 0; dc < 4; ++dc)
#pragma unroll
      for (int ks = 0; ks < 4; ++ks) {
        bf16x8 pf = *(const bf16x8*)&Pl[w * 16 + fr][ks * 32 + fg * 8];
        bf16x8 vf = *(const bf16x8*)&Vt[dc * 16 + fr][ks * 32 + fg * 8];
        o[dc] = __builtin_amdgcn_mfma_f32_16x16x32_bf16(pf, vf, o[dc], 0, 0, 0);
      }
  }

  // ---- epilogue: ctx = o / l ----
#pragma unroll
  for (int dc = 0; dc < 4; ++dc)
#pragma unroll
    for (int r = 0; r < 4; ++r) {
      const int qg = qt * 64 + w * 16 + fg * 4 + r;
      const float v = o[dc][r] / lrow[r];
      ctxb[((size_t)(b * SS + qg) * DD) + h * DHD + dc * 16 + fr] = f2bf(v);
    }
}

// ================= host launch =================
extern "C" void kernel_launch(void* const* d_in, const int* in_sizes, int n_in,
                              void* d_out, int out_size, void* d_ws, size_t ws_size,
                              hipStream_t stream) {
  const int*   ids   = (const int*)d_in[0];
  const float* amask = (const float*)d_in[1];
  const float* wemb  = (const float*)d_in[2];
  const float* pemb  = (const float*)d_in[3];
  const float* eln_w = (const float*)d_in[4];
  const float* eln_b = (const float*)d_in[5];
  const float* relt  = (const float*)d_in[6];
  const float* Wq    = (const float*)d_in[7];
  const float* bq    = (const float*)d_in[8];
  const float* Wk    = (const float*)d_in[9];
  const float* bk    = (const float*)d_in[10];
  const float* Wv    = (const float*)d_in[11];
  const float* bv    = (const float*)d_in[12];
  const float* Wo    = (const float*)d_in[13];
  const float* bo    = (const float*)d_in[14];
  const float* aln_w = (const float*)d_in[15];
  const float* aln_b = (const float*)d_in[16];
  const float* Wi    = (const float*)d_in[17];
  const float* bi    = (const float*)d_in[18];
  const float* Wd    = (const float*)d_in[19];
  const float* bd    = (const float*)d_in[20];
  const float* oln_w = (const float*)d_in[21];
  const float* oln_b = (const float*)d_in[22];

  size_t off = 0;
  auto carve = [&](size_t bytes) -> void* {
    void* r = (char*)d_ws + off;
    off += (bytes + 255) & ~(size_t)255;
    return r;
  };
  float*  hf     = (float*) carve((size_t)MM * DD * 4);
  ushort* hb     = (ushort*)carve((size_t)MM * DD * 2);
  ushort* qbuf   = (ushort*)carve((size_t)MM * DD * 2);
  ushort* kbuf   = (ushort*)carve((size_t)MM * DD * 2);
  ushort* vbuf   = (ushort*)carve((size_t)MM * DD * 2);
  ushort* ctxb   = (ushort*)carve((size_t)MM * DD * 2);
  float*  gout   = (float*) carve((size_t)MM * DD * 4);
  ushort* interb = (ushort*)carve((size_t)MM * FF * 2);

  embed_ln_kernel<<<MM, 256, 0, stream>>>(ids, wemb, pemb, eln_w, eln_b, hf, hb);

  const dim3 gD(MM / 128, DD / 128);   // 64 x 6
  const dim3 gF(MM / 128, FF / 128);   // 64 x 24
  const dim3 gA(SS / 64, BB * HH);     // 8 x 192

  for (int l = 0; l < LL; ++l) {
    const size_t wo  = (size_t)l * DD * DD;
    const size_t wio = (size_t)l * FF * DD;

    gemm_bt<0><<<gD, 256, 0, stream>>>(hb, Wq + wo, bq + l * DD, qbuf, DD, DD);
    gemm_bt<0><<<gD, 256, 0, stream>>>(hb, Wk + wo, bk + l * DD, kbuf, DD, DD);
    gemm_bt<0><<<gD, 256, 0, stream>>>(hb, Wv + wo, bv + l * DD, vbuf, DD, DD);

    attn_kernel<<<gA, 256, 0, stream>>>(qbuf, kbuf, vbuf, relt, amask, ctxb);

    gemm_bt<1><<<gD, 256, 0, stream>>>(ctxb, Wo + wo, bo + l * DD, gout, DD, DD);
    add_ln_kernel<<<MM, 256, 0, stream>>>(hf, gout, aln_w + l * DD, aln_b + l * DD, hf, hb);

    gemm_bt<2><<<gF, 256, 0, stream>>>(hb, Wi + wio, bi + l * FF, interb, FF, DD);
    gemm_bt<1><<<gD, 256, 0, stream>>>(interb, Wd + wio, bd + l * DD, gout, DD, FF);

    float* outp = (l == LL - 1) ? (float*)d_out : hf;
    add_ln_kernel<<<MM, 256, 0, stream>>>(hf, gout, oln_w + l * DD, oln_b + l * DD, outp, hb);
  }
}

// Round 3
// 4002.570 us; speedup vs baseline: 1.4316x; 1.4316x over previous
//
#include <hip/hip_runtime.h>
#include <cstdint>
#include <cstddef>

// ---------------- config ----------------
#define BB 16
#define SS 512
#define DD 768
#define HH 12
#define FF 3072
#define LL 12
#define DHD 64
#define MM (BB*SS)   // 8192 rows

typedef __attribute__((ext_vector_type(8))) short bf16x8;
typedef __attribute__((ext_vector_type(4))) float f32x4;

__device__ __forceinline__ ushort f2bf(float f) {
  union { float f; uint32_t u; } x; x.f = f;
  uint32_t r = x.u + 0x7FFFu + ((x.u >> 16) & 1u);
  return (ushort)(r >> 16);
}

__device__ __forceinline__ void glds16(const ushort* g, ushort* l) {
  __builtin_amdgcn_global_load_lds((__attribute__((address_space(1))) void*)g,
                                   (__attribute__((address_space(3))) void*)l,
                                   16, 0, 0);
}

// ================= weight f32 -> bf16 conversion (up to 4 tensors) =================
__global__ __launch_bounds__(256)
void convw4(const float* __restrict__ s0, const float* __restrict__ s1,
            const float* __restrict__ s2, const float* __restrict__ s3,
            ushort* __restrict__ dst, int per)
{
  const float* s = blockIdx.y == 0 ? s0 : blockIdx.y == 1 ? s1 : blockIdx.y == 2 ? s2 : s3;
  const int i = (blockIdx.x * 256 + threadIdx.x) * 4;
  if (i >= per) return;
  const float4 v = *(const float4*)(s + i);
  ushort4 o;
  o.x = f2bf(v.x); o.y = f2bf(v.y); o.z = f2bf(v.z); o.w = f2bf(v.w);
  *(ushort4*)(dst + (size_t)blockIdx.y * per + i) = o;
}

// ================= embedding + LayerNorm =================
__global__ __launch_bounds__(256)
void embed_ln_kernel(const int* __restrict__ ids, const float* __restrict__ wemb,
                     const float* __restrict__ pemb, const float* __restrict__ g,
                     const float* __restrict__ bt, float* __restrict__ hf,
                     ushort* __restrict__ hb)
{
  const int row = blockIdx.x;
  const int s = row & (SS - 1);
  const int id = ids[row];
  const float* wp = wemb + (size_t)id * DD;
  const float* pp = pemb + (size_t)s * DD;
  const int tid = threadIdx.x;
  float v[3]; float sum = 0.f, sq = 0.f;
#pragma unroll
  for (int j = 0; j < 3; ++j) {
    int e = tid + j * 256;
    v[j] = wp[e] + pp[e];
    sum += v[j]; sq += v[j] * v[j];
  }
  __shared__ float red[2][4];
#pragma unroll
  for (int off = 32; off >= 1; off >>= 1) { sum += __shfl_xor(sum, off); sq += __shfl_xor(sq, off); }
  const int lane = tid & 63, wid = tid >> 6;
  if (lane == 0) { red[0][wid] = sum; red[1][wid] = sq; }
  __syncthreads();
  sum = red[0][0] + red[0][1] + red[0][2] + red[0][3];
  sq  = red[1][0] + red[1][1] + red[1][2] + red[1][3];
  const float mean = sum * (1.f / DD);
  const float var  = sq  * (1.f / DD) - mean * mean;
  const float rstd = rsqrtf(var + 1e-12f);
  const size_t base = (size_t)row * DD;
#pragma unroll
  for (int j = 0; j < 3; ++j) {
    int e = tid + j * 256;
    float o = (v[j] - mean) * rstd * g[e] + bt[e];
    hf[base + e] = o;
    hb[base + e] = f2bf(o);
  }
}

// ================= residual add + LayerNorm =================
__global__ __launch_bounds__(256)
void add_ln_kernel(const float* __restrict__ res, const float* __restrict__ add,
                   const float* __restrict__ g, const float* __restrict__ bt,
                   float* __restrict__ hf, ushort* __restrict__ hb)
{
  const int row = blockIdx.x;
  const int tid = threadIdx.x;
  const size_t base = (size_t)row * DD;
  float v[3]; float sum = 0.f, sq = 0.f;
#pragma unroll
  for (int j = 0; j < 3; ++j) {
    int e = tid + j * 256;
    v[j] = res[base + e] + add[base + e];
    sum += v[j]; sq += v[j] * v[j];
  }
  __shared__ float red[2][4];
#pragma unroll
  for (int off = 32; off >= 1; off >>= 1) { sum += __shfl_xor(sum, off); sq += __shfl_xor(sq, off); }
  const int lane = tid & 63, wid = tid >> 6;
  if (lane == 0) { red[0][wid] = sum; red[1][wid] = sq; }
  __syncthreads();
  sum = red[0][0] + red[0][1] + red[0][2] + red[0][3];
  sq  = red[1][0] + red[1][1] + red[1][2] + red[1][3];
  const float mean = sum * (1.f / DD);
  const float var  = sq  * (1.f / DD) - mean * mean;
  const float rstd = rsqrtf(var + 1e-12f);
#pragma unroll
  for (int j = 0; j < 3; ++j) {
    int e = tid + j * 256;
    float o = (v[j] - mean) * rstd * g[e] + bt[e];
    hf[base + e] = o;
    hb[base + e] = f2bf(o);
  }
}

// ================= GEMM: C[M,N] = A[M,K](bf16) @ Bw[N,K](bf16)^T + bias =================
// m97 structure: 128x128 tile, BK=32, global_load_lds width-16 staging,
// linear LDS [128][32], double-buffered, one barrier per K-step.
// nsub sub-outputs along N (QKV fusion): grid.y = nsub*nblk, each sub is [M, nblk*128].
// EPI 0: bf16 out + bias;  1: f32 out + bias;  2: bf16 out + bias + exact gelu
template<int EPI>
__global__ __launch_bounds__(256, 2)
void gemm_ker(const ushort* __restrict__ A,
              const ushort* __restrict__ B0, const ushort* __restrict__ B1,
              const ushort* __restrict__ B2,
              const float* __restrict__ bias0, const float* __restrict__ bias1,
              const float* __restrict__ bias2,
              void* __restrict__ C0, void* __restrict__ C1, void* __restrict__ C2,
              int Kdim, int nblk)
{
  __shared__ ushort As[2][128 * 32];
  __shared__ ushort Bs[2][128 * 32];

  // bijective XCD swizzle (nwg divisible by 8 for all our grids)
  int id = blockIdx.y * gridDim.x + blockIdx.x;
  const int chunk = (gridDim.x * gridDim.y) >> 3;
  id = (id & 7) * chunk + (id >> 3);
  const int bm = id & 63;        // gridDim.x == 64 (8192/128)
  const int bnAll = id >> 6;
  const int sub = bnAll / nblk;
  const int bn = bnAll - sub * nblk;

  const ushort* Bw  = sub == 0 ? B0 : (sub == 1 ? B1 : B2);
  const float* bias = sub == 0 ? bias0 : (sub == 1 ? bias1 : bias2);
  void* Cout        = sub == 0 ? C0 : (sub == 1 ? C1 : C2);
  const int Ndim = nblk * 128;

  const int tid = threadIdx.x;
  const int l = tid & 63, w = tid >> 6;
  const int wm = w >> 1, wn = w & 1;
  const int fr = l & 15, fg = l >> 4;

  // staging: per wave 2 instrs per tensor; lane l -> row w*32 + i*16 + l/4, col (l&3)*8
  const int srow = l >> 2;
  const int scol = (l & 3) * 8;
  const ushort* Agl = A  + (size_t)(bm * 128 + w * 32 + srow) * Kdim + scol;
  const ushort* Bgl = Bw + (size_t)(bn * 128 + w * 32 + srow) * Kdim + scol;
  ushort* AsW = &As[0][(w * 32) * 32];
  ushort* BsW = &Bs[0][(w * 32) * 32];

  auto stage = [&](int buf, int kt) {
    const ushort* a = Agl + kt * 32;
    const ushort* b = Bgl + kt * 32;
    ushort* al = AsW + buf * 4096;
    ushort* bl = BsW + buf * 4096;
    glds16(a,                   al);
    glds16(a + 16 * (size_t)Kdim, al + 512);
    glds16(b,                   bl);
    glds16(b + 16 * (size_t)Kdim, bl + 512);
  };

  f32x4 acc[4][4];
#pragma unroll
  for (int i = 0; i < 4; ++i)
#pragma unroll
    for (int j = 0; j < 4; ++j) acc[i][j] = f32x4{0.f, 0.f, 0.f, 0.f};

  stage(0, 0);
  __syncthreads();
  const int nk = Kdim >> 5;
  int cur = 0;
  for (int kt = 0; kt < nk; ++kt) {
    if (kt + 1 < nk) stage(cur ^ 1, kt + 1);
    bf16x8 af[4], bfv[4];
#pragma unroll
    for (int i = 0; i < 4; ++i) af[i]  = *(const bf16x8*)&As[cur][(wm * 64 + i * 16 + fr) * 32 + fg * 8];
#pragma unroll
    for (int j = 0; j < 4; ++j) bfv[j] = *(const bf16x8*)&Bs[cur][(wn * 64 + j * 16 + fr) * 32 + fg * 8];
#pragma unroll
    for (int i = 0; i < 4; ++i)
#pragma unroll
      for (int j = 0; j < 4; ++j)
        acc[i][j] = __builtin_amdgcn_mfma_f32_16x16x32_bf16(af[i], bfv[j], acc[i][j], 0, 0, 0);
    __syncthreads();
    cur ^= 1;
  }

#pragma unroll
  for (int i = 0; i < 4; ++i) {
    const int row0 = bm * 128 + wm * 64 + i * 16 + fg * 4;
#pragma unroll
    for (int j = 0; j < 4; ++j) {
      const int col = bn * 128 + wn * 64 + j * 16 + fr;
      const float bv = bias[col];
#pragma unroll
      for (int r = 0; r < 4; ++r) {
        float v = acc[i][j][r] + bv;
        if (EPI == 2) v = 0.5f * v * (1.0f + erff(v * 0.70710678118f));
        if (EPI == 1) ((float*)Cout)[(size_t)(row0 + r) * Ndim + col] = v;
        else          ((ushort*)Cout)[(size_t)(row0 + r) * Ndim + col] = f2bf(v);
      }
    }
  }
}

// ================= fused flash attention =================
__global__ __launch_bounds__(256, 2)
void attn_kernel(const ushort* __restrict__ qb, const ushort* __restrict__ kb,
                 const ushort* __restrict__ vb, const float* __restrict__ relt,
                 const float* __restrict__ amask, ushort* __restrict__ ctxb)
{
  __shared__ ushort Kt[128][72];
  __shared__ ushort Vt[64][136];
  __shared__ ushort Pl[64][136];

  const int tid = threadIdx.x, lane = tid & 63, w = tid >> 6;
  const int qt = blockIdx.x, bh = blockIdx.y;
  const int b = bh / HH, h = bh % HH;
  const int fr = lane & 15, fg = lane >> 4;

  bf16x8 qf[2];
  {
    const int qrow = qt * 64 + w * 16 + fr;
    const ushort* p = qb + ((size_t)(b * SS + qrow) * DD) + h * DHD + fg * 8;
    qf[0] = *(const bf16x8*)p;
    qf[1] = *(const bf16x8*)(p + 32);
  }

  f32x4 o[4];
  float mrow[4], lrow[4];
#pragma unroll
  for (int r = 0; r < 4; ++r) { mrow[r] = -1e30f; lrow[r] = 0.f; }
#pragma unroll
  for (int d = 0; d < 4; ++d) o[d] = f32x4{0.f, 0.f, 0.f, 0.f};

  const int skr = tid >> 1;
  const int shd = (tid & 1) * 32;

  for (int kt = 0; kt < 4; ++kt) {
    const size_t gbase = ((size_t)(b * SS + kt * 128 + skr) * DD) + h * DHD + shd;
    int4 kr0 = *(const int4*)(kb + gbase);
    int4 kr1 = *(const int4*)(kb + gbase + 8);
    int4 kr2 = *(const int4*)(kb + gbase + 16);
    int4 kr3 = *(const int4*)(kb + gbase + 24);
    int4 vr0 = *(const int4*)(vb + gbase);
    int4 vr1 = *(const int4*)(vb + gbase + 8);
    int4 vr2 = *(const int4*)(vb + gbase + 16);
    int4 vr3 = *(const int4*)(vb + gbase + 24);

    __syncthreads();
    *(int4*)&Kt[skr][shd]      = kr0;
    *(int4*)&Kt[skr][shd + 8]  = kr1;
    *(int4*)&Kt[skr][shd + 16] = kr2;
    *(int4*)&Kt[skr][shd + 24] = kr3;
    {
      union { int4 v; ushort u[8]; } t;
      t.v = vr0;
#pragma unroll
      for (int e = 0; e < 8; ++e) Vt[shd + e][skr] = t.u[e];
      t.v = vr1;
#pragma unroll
      for (int e = 0; e < 8; ++e) Vt[shd + 8 + e][skr] = t.u[e];
      t.v = vr2;
#pragma unroll
      for (int e = 0; e < 8; ++e) Vt[shd + 16 + e][skr] = t.u[e];
      t.v = vr3;
#pragma unroll
      for (int e = 0; e < 8; ++e) Vt[shd + 24 + e][skr] = t.u[e];
    }
    __syncthreads();

    float sv[8][4];
#pragma unroll
    for (int kc = 0; kc < 8; ++kc) {
      f32x4 s = f32x4{0.f, 0.f, 0.f, 0.f};
      bf16x8 kf0 = *(const bf16x8*)&Kt[kc * 16 + fr][fg * 8];
      bf16x8 kf1 = *(const bf16x8*)&Kt[kc * 16 + fr][32 + fg * 8];
      s = __builtin_amdgcn_mfma_f32_16x16x32_bf16(qf[0], kf0, s, 0, 0, 0);
      s = __builtin_amdgcn_mfma_f32_16x16x32_bf16(qf[1], kf1, s, 0, 0, 0);
      const int col = kt * 128 + kc * 16 + fr;
      const float am = (1.0f - amask[b * SS + col]) * -10000.0f;
#pragma unroll
      for (int r = 0; r < 4; ++r) {
        const int qg = qt * 64 + w * 16 + fg * 4 + r;
        int rel = col - qg;
        rel = min(128, max(-128, rel)) + 128;
        sv[kc][r] = s[r] * 0.125f + relt[rel * HH + h] + am;
      }
    }

    float ef[4];
#pragma unroll
    for (int r = 0; r < 4; ++r) {
      float tmax = sv[0][r];
#pragma unroll
      for (int kc = 1; kc < 8; ++kc) tmax = fmaxf(tmax, sv[kc][r]);
#pragma unroll
      for (int off = 1; off < 16; off <<= 1) tmax = fmaxf(tmax, __shfl_xor(tmax, off));
      const float mnew = fmaxf(mrow[r], tmax);
      ef[r] = __expf(mrow[r] - mnew);
      float psum = 0.f;
      const int prow = w * 16 + fg * 4 + r;
#pragma unroll
      for (int kc = 0; kc < 8; ++kc) {
        float p = __expf(sv[kc][r] - mnew);
        psum += p;
        Pl[prow][kc * 16 + fr] = f2bf(p);
      }
#pragma unroll
      for (int off = 1; off < 16; off <<= 1) psum += __shfl_xor(psum, off);
      lrow[r] = lrow[r] * ef[r] + psum;
      mrow[r] = mnew;
    }
#pragma unroll
    for (int dc = 0; dc < 4; ++dc)
#pragma unroll
      for (int r = 0; r < 4; ++r) o[dc][r] *= ef[r];
    __syncthreads();

#pragma unroll
    for (int dc = 0; dc < 4; ++dc)
#pragma unroll
      for (int ks = 0; ks < 4; ++ks) {
        bf16x8 pf = *(const bf16x8*)&Pl[w * 16 + fr][ks * 32 + fg * 8];
        bf16x8 vf = *(const bf16x8*)&Vt[dc * 16 + fr][ks * 32 + fg * 8];
        o[dc] = __builtin_amdgcn_mfma_f32_16x16x32_bf16(pf, vf, o[dc], 0, 0, 0);
      }
  }

#pragma unroll
  for (int dc = 0; dc < 4; ++dc)
#pragma unroll
    for (int r = 0; r < 4; ++r) {
      const int qg = qt * 64 + w * 16 + fg * 4 + r;
      const float v = o[dc][r] / lrow[r];
      ctxb[((size_t)(b * SS + qg) * DD) + h * DHD + dc * 16 + fr] = f2bf(v);
    }
}

// ================= host launch =================
extern "C" void kernel_launch(void* const* d_in, const int* in_sizes, int n_in,
                              void* d_out, int out_size, void* d_ws, size_t ws_size,
                              hipStream_t stream) {
  const int*   ids   = (const int*)d_in[0];
  const float* amask = (const float*)d_in[1];
  const float* wemb  = (const float*)d_in[2];
  const float* pemb  = (const float*)d_in[3];
  const float* eln_w = (const float*)d_in[4];
  const float* eln_b = (const float*)d_in[5];
  const float* relt  = (const float*)d_in[6];
  const float* Wq    = (const float*)d_in[7];
  const float* bq    = (const float*)d_in[8];
  const float* Wk    = (const float*)d_in[9];
  const float* bk    = (const float*)d_in[10];
  const float* Wv    = (const float*)d_in[11];
  const float* bv    = (const float*)d_in[12];
  const float* Wo    = (const float*)d_in[13];
  const float* bo    = (const float*)d_in[14];
  const float* aln_w = (const float*)d_in[15];
  const float* aln_b = (const float*)d_in[16];
  const float* Wi    = (const float*)d_in[17];
  const float* bi    = (const float*)d_in[18];
  const float* Wd    = (const float*)d_in[19];
  const float* bd    = (const float*)d_in[20];
  const float* oln_w = (const float*)d_in[21];
  const float* oln_b = (const float*)d_in[22];

  size_t off = 0;
  auto carve = [&](size_t bytes) -> void* {
    void* r = (char*)d_ws + off;
    off += (bytes + 255) & ~(size_t)255;
    return r;
  };
  float*  hf     = (float*) carve((size_t)MM * DD * 4);
  ushort* hb     = (ushort*)carve((size_t)MM * DD * 2);
  ushort* qbuf   = (ushort*)carve((size_t)MM * DD * 2);
  ushort* kbuf   = (ushort*)carve((size_t)MM * DD * 2);
  ushort* vbuf   = (ushort*)carve((size_t)MM * DD * 2);
  ushort* ctxb   = (ushort*)carve((size_t)MM * DD * 2);
  float*  gout   = (float*) carve((size_t)MM * DD * 4);
  ushort* interb = (ushort*)carve((size_t)MM * FF * 2);

  // weight bf16 staging regions (time-shared with dead windows of other buffers):
  //  wA (Wq,Wk,Wv,Wo bf16, 4*589824 elems = 4.7MB) lives in interb
  //    [written at layer start; consumed by QKV & O GEMMs; interb activations
  //     only written later by the Wi GEMM]
  //  wB (Wi,Wd bf16, 2*2359296 elems = 9.4MB) lives in qbuf..kbuf region
  //    [written after attn has consumed q/k/v; consumed by Wi/Wd GEMMs;
  //     qbuf next written by the following layer's QKV GEMM]
  ushort* wA = interb;
  ushort* wB = qbuf;
  const int PD = DD * DD;   // 589824
  const int PF = FF * DD;   // 2359296

  embed_ln_kernel<<<MM, 256, 0, stream>>>(ids, wemb, pemb, eln_w, eln_b, hf, hb);

  const dim3 gQKV(MM / 128, 3 * (DD / 128));  // 64 x 18
  const dim3 gD(MM / 128, DD / 128);          // 64 x 6
  const dim3 gF(MM / 128, FF / 128);          // 64 x 24
  const dim3 gA(SS / 64, BB * HH);            // 8 x 192
  const dim3 gCA(PD / 1024, 4);               // 576 x 4
  const dim3 gCB(PF / 1024, 2);               // 2304 x 2

  for (int l = 0; l < LL; ++l) {
    const size_t wo  = (size_t)l * PD;
    const size_t wio = (size_t)l * PF;

    // convert Wq,Wk,Wv,Wo -> bf16 (into interb's dead window)
    convw4<<<gCA, 256, 0, stream>>>(Wq + wo, Wk + wo, Wv + wo, Wo + wo, wA, PD);

    // fused QKV GEMM
    gemm_ker<0><<<gQKV, 256, 0, stream>>>(hb, wA, wA + PD, wA + 2 * PD,
                                          bq + l * DD, bk + l * DD, bv + l * DD,
                                          qbuf, kbuf, vbuf, DD, DD / 128);

    attn_kernel<<<gA, 256, 0, stream>>>(qbuf, kbuf, vbuf, relt, amask, ctxb);

    // convert Wi,Wd -> bf16 (into qbuf's dead window, after attn)
    convw4<<<gCB, 256, 0, stream>>>(Wi + wio, Wd + wio, Wi + wio, Wi + wio, wB, PF);

    gemm_ker<1><<<gD, 256, 0, stream>>>(ctxb, wA + 3 * PD, wA + 3 * PD, wA + 3 * PD,
                                        bo + l * DD, bo + l * DD, bo + l * DD,
                                        gout, gout, gout, DD, DD / 128);
    add_ln_kernel<<<MM, 256, 0, stream>>>(hf, gout, aln_w + l * DD, aln_b + l * DD, hf, hb);

    gemm_ker<2><<<gF, 256, 0, stream>>>(hb, wB, wB, wB,
                                        bi + l * FF, bi + l * FF, bi + l * FF,
                                        interb, interb, interb, DD, FF / 128);
    gemm_ker<1><<<gD, 256, 0, stream>>>(interb, wB + PF, wB + PF, wB + PF,
                                        bd + l * DD, bd + l * DD, bd + l * DD,
                                        gout, gout, gout, FF, DD / 128);

    float* outp = (l == LL - 1) ? (float*)d_out : hf;
    add_ln_kernel<<<MM, 256, 0, stream>>>(hf, gout, oln_w + l * DD, oln_b + l * DD, outp, hb);
  }
}

// Round 4
// 3697.717 us; speedup vs baseline: 1.5497x; 1.0824x over previous
//
#include <hip/hip_runtime.h>
#include <cstdint>
#include <cstddef>

// ---------------- config ----------------
#define BB 16
#define SS 512
#define DD 768
#define HH 12
#define FF 3072
#define LL 12
#define DHD 64
#define MM (BB*SS)   // 8192 rows

typedef __attribute__((ext_vector_type(8))) short bf16x8;
typedef __attribute__((ext_vector_type(4))) float f32x4;

__device__ __forceinline__ ushort f2bf(float f) {
  union { float f; uint32_t u; } x; x.f = f;
  uint32_t r = x.u + 0x7FFFu + ((x.u >> 16) & 1u);
  return (ushort)(r >> 16);
}

__device__ __forceinline__ void glds16(const ushort* g, ushort* l) {
  __builtin_amdgcn_global_load_lds((__attribute__((address_space(1))) void*)g,
                                   (__attribute__((address_space(3))) void*)l,
                                   16, 0, 0);
}

// ================= weight f32 -> bf16 conversion (up to 4 tensors) =================
__global__ __launch_bounds__(256)
void convw4(const float* __restrict__ s0, const float* __restrict__ s1,
            const float* __restrict__ s2, const float* __restrict__ s3,
            ushort* __restrict__ dst, int per)
{
  const float* s = blockIdx.y == 0 ? s0 : blockIdx.y == 1 ? s1 : blockIdx.y == 2 ? s2 : s3;
  const int i = (blockIdx.x * 256 + threadIdx.x) * 4;
  if (i >= per) return;
  const float4 v = *(const float4*)(s + i);
  ushort4 o;
  o.x = f2bf(v.x); o.y = f2bf(v.y); o.z = f2bf(v.z); o.w = f2bf(v.w);
  *(ushort4*)(dst + (size_t)blockIdx.y * per + i) = o;
}

// ================= embedding + LayerNorm =================
__global__ __launch_bounds__(256)
void embed_ln_kernel(const int* __restrict__ ids, const float* __restrict__ wemb,
                     const float* __restrict__ pemb, const float* __restrict__ g,
                     const float* __restrict__ bt, float* __restrict__ hf,
                     ushort* __restrict__ hb)
{
  const int row = blockIdx.x;
  const int s = row & (SS - 1);
  const int id = ids[row];
  const float* wp = wemb + (size_t)id * DD;
  const float* pp = pemb + (size_t)s * DD;
  const int tid = threadIdx.x;
  float v[3]; float sum = 0.f, sq = 0.f;
#pragma unroll
  for (int j = 0; j < 3; ++j) {
    int e = tid + j * 256;
    v[j] = wp[e] + pp[e];
    sum += v[j]; sq += v[j] * v[j];
  }
  __shared__ float red[2][4];
#pragma unroll
  for (int off = 32; off >= 1; off >>= 1) { sum += __shfl_xor(sum, off); sq += __shfl_xor(sq, off); }
  const int lane = tid & 63, wid = tid >> 6;
  if (lane == 0) { red[0][wid] = sum; red[1][wid] = sq; }
  __syncthreads();
  sum = red[0][0] + red[0][1] + red[0][2] + red[0][3];
  sq  = red[1][0] + red[1][1] + red[1][2] + red[1][3];
  const float mean = sum * (1.f / DD);
  const float var  = sq  * (1.f / DD) - mean * mean;
  const float rstd = rsqrtf(var + 1e-12f);
  const size_t base = (size_t)row * DD;
#pragma unroll
  for (int j = 0; j < 3; ++j) {
    int e = tid + j * 256;
    float o = (v[j] - mean) * rstd * g[e] + bt[e];
    hf[base + e] = o;
    hb[base + e] = f2bf(o);
  }
}

// ================= residual add + LayerNorm =================
__global__ __launch_bounds__(256)
void add_ln_kernel(const float* __restrict__ res, const float* __restrict__ add,
                   const float* __restrict__ g, const float* __restrict__ bt,
                   float* __restrict__ hf, ushort* __restrict__ hb)
{
  const int row = blockIdx.x;
  const int tid = threadIdx.x;
  const size_t base = (size_t)row * DD;
  float v[3]; float sum = 0.f, sq = 0.f;
#pragma unroll
  for (int j = 0; j < 3; ++j) {
    int e = tid + j * 256;
    v[j] = res[base + e] + add[base + e];
    sum += v[j]; sq += v[j] * v[j];
  }
  __shared__ float red[2][4];
#pragma unroll
  for (int off = 32; off >= 1; off >>= 1) { sum += __shfl_xor(sum, off); sq += __shfl_xor(sq, off); }
  const int lane = tid & 63, wid = tid >> 6;
  if (lane == 0) { red[0][wid] = sum; red[1][wid] = sq; }
  __syncthreads();
  sum = red[0][0] + red[0][1] + red[0][2] + red[0][3];
  sq  = red[1][0] + red[1][1] + red[1][2] + red[1][3];
  const float mean = sum * (1.f / DD);
  const float var  = sq  * (1.f / DD) - mean * mean;
  const float rstd = rsqrtf(var + 1e-12f);
#pragma unroll
  for (int j = 0; j < 3; ++j) {
    int e = tid + j * 256;
    float o = (v[j] - mean) * rstd * g[e] + bt[e];
    hf[base + e] = o;
    hb[base + e] = f2bf(o);
  }
}

// ================= GEMM: C[M,N] = A[M,K](bf16) @ Bw[N,K](bf16)^T + bias =================
// m97 structure. TRV: sub==2 output written transposed as vT[b][h][d][s].
template<int EPI, bool TRV>
__global__ __launch_bounds__(256, 2)
void gemm_ker(const ushort* __restrict__ A,
              const ushort* __restrict__ B0, const ushort* __restrict__ B1,
              const ushort* __restrict__ B2,
              const float* __restrict__ bias0, const float* __restrict__ bias1,
              const float* __restrict__ bias2,
              void* __restrict__ C0, void* __restrict__ C1, void* __restrict__ C2,
              int Kdim, int nblk)
{
  __shared__ ushort As[2][128 * 32];
  __shared__ ushort Bs[2][128 * 32];

  int id = blockIdx.y * gridDim.x + blockIdx.x;
  const int chunk = (gridDim.x * gridDim.y) >> 3;
  id = (id & 7) * chunk + (id >> 3);
  const int bm = id & 63;
  const int bnAll = id >> 6;
  const int sub = bnAll / nblk;
  const int bn = bnAll - sub * nblk;

  const ushort* Bw  = sub == 0 ? B0 : (sub == 1 ? B1 : B2);
  const float* bias = sub == 0 ? bias0 : (sub == 1 ? bias1 : bias2);
  void* Cout        = sub == 0 ? C0 : (sub == 1 ? C1 : C2);
  const int Ndim = nblk * 128;

  const int tid = threadIdx.x;
  const int l = tid & 63, w = tid >> 6;
  const int wm = w >> 1, wn = w & 1;
  const int fr = l & 15, fg = l >> 4;

  const int srow = l >> 2;
  const int scol = (l & 3) * 8;
  const ushort* Agl = A  + (size_t)(bm * 128 + w * 32 + srow) * Kdim + scol;
  const ushort* Bgl = Bw + (size_t)(bn * 128 + w * 32 + srow) * Kdim + scol;
  ushort* AsW = &As[0][(w * 32) * 32];
  ushort* BsW = &Bs[0][(w * 32) * 32];

  auto stage = [&](int buf, int kt) {
    const ushort* a = Agl + kt * 32;
    const ushort* b = Bgl + kt * 32;
    ushort* al = AsW + buf * 4096;
    ushort* bl = BsW + buf * 4096;
    glds16(a,                     al);
    glds16(a + 16 * (size_t)Kdim, al + 512);
    glds16(b,                     bl);
    glds16(b + 16 * (size_t)Kdim, bl + 512);
  };

  f32x4 acc[4][4];
#pragma unroll
  for (int i = 0; i < 4; ++i)
#pragma unroll
    for (int j = 0; j < 4; ++j) acc[i][j] = f32x4{0.f, 0.f, 0.f, 0.f};

  stage(0, 0);
  __syncthreads();
  const int nk = Kdim >> 5;
  int cur = 0;
  for (int kt = 0; kt < nk; ++kt) {
    if (kt + 1 < nk) stage(cur ^ 1, kt + 1);
    bf16x8 af[4], bfv[4];
#pragma unroll
    for (int i = 0; i < 4; ++i) af[i]  = *(const bf16x8*)&As[cur][(wm * 64 + i * 16 + fr) * 32 + fg * 8];
#pragma unroll
    for (int j = 0; j < 4; ++j) bfv[j] = *(const bf16x8*)&Bs[cur][(wn * 64 + j * 16 + fr) * 32 + fg * 8];
#pragma unroll
    for (int i = 0; i < 4; ++i)
#pragma unroll
      for (int j = 0; j < 4; ++j)
        acc[i][j] = __builtin_amdgcn_mfma_f32_16x16x32_bf16(af[i], bfv[j], acc[i][j], 0, 0, 0);
    __syncthreads();
    cur ^= 1;
  }

#pragma unroll
  for (int i = 0; i < 4; ++i) {
    const int row0 = bm * 128 + wm * 64 + i * 16 + fg * 4;
#pragma unroll
    for (int j = 0; j < 4; ++j) {
      const int col = bn * 128 + wn * 64 + j * 16 + fr;
      const float bv = bias[col];
      if (TRV && sub == 2) {
        // V output transposed: vT[((b*H + h)*DH + d)*S + s], rows are contiguous s
        const int h_ = col >> 6, d_ = col & 63;
        const int b_ = row0 >> 9, s_ = row0 & 511;
        ushort4 o4;
        o4.x = f2bf(acc[i][j][0] + bv);
        o4.y = f2bf(acc[i][j][1] + bv);
        o4.z = f2bf(acc[i][j][2] + bv);
        o4.w = f2bf(acc[i][j][3] + bv);
        *(ushort4*)((ushort*)Cout + (((size_t)(b_ * HH + h_) * DHD + d_) * SS + s_)) = o4;
      } else {
#pragma unroll
        for (int r = 0; r < 4; ++r) {
          float v = acc[i][j][r] + bv;
          if (EPI == 2) v = 0.5f * v * (1.0f + erff(v * 0.70710678118f));
          if (EPI == 1) ((float*)Cout)[(size_t)(row0 + r) * Ndim + col] = v;
          else          ((ushort*)Cout)[(size_t)(row0 + r) * Ndim + col] = f2bf(v);
        }
      }
    }
  }
}

// ================= fused flash attention (V pre-transposed) =================
__global__ __launch_bounds__(256, 2)
void attn_kernel(const ushort* __restrict__ qb, const ushort* __restrict__ kb,
                 const ushort* __restrict__ vt, const float* __restrict__ relt,
                 const float* __restrict__ amask, ushort* __restrict__ ctxb)
{
  __shared__ ushort Kt[128][72];
  __shared__ ushort Vt[64][136];
  __shared__ ushort Pl[64][136];
  __shared__ float am_lds[512];
  __shared__ float rel_lds[1024];

  const int tid = threadIdx.x, lane = tid & 63, w = tid >> 6;

  // XCD-chunked swizzle: all 8 q-tiles of one (b,h) land on one XCD
  int lin = blockIdx.y * gridDim.x + blockIdx.x;        // 0..1535
  lin = (lin & 7) * 192 + (lin >> 3);
  const int qt = lin & 7;
  const int bh = lin >> 3;
  const int b = bh / HH, h = bh - b * HH;
  const int fr = lane & 15, fg = lane >> 4;

  // LDS tables: additive mask row + pre-clipped rel-bias line for head h
  for (int i = tid; i < 512; i += 256)
    am_lds[i] = (1.0f - amask[b * SS + i]) * -10000.0f;
  for (int i = tid; i < 1024; i += 256) {
    int d = i - 512;                       // col - qg
    d = min(128, max(-128, d));
    rel_lds[i] = relt[(d + 128) * HH + h];
  }

  bf16x8 qf[2];
  {
    const int qrow = qt * 64 + w * 16 + fr;
    const ushort* p = qb + ((size_t)(b * SS + qrow) * DD) + h * DHD + fg * 8;
    qf[0] = *(const bf16x8*)p;
    qf[1] = *(const bf16x8*)(p + 32);
  }

  f32x4 o[4];
  float mrow[4], lrow[4];
#pragma unroll
  for (int r = 0; r < 4; ++r) { mrow[r] = -1e30f; lrow[r] = 0.f; }
#pragma unroll
  for (int d = 0; d < 4; ++d) o[d] = f32x4{0.f, 0.f, 0.f, 0.f};

  const int skr = tid >> 1;            // K staging row 0..127
  const int shd = (tid & 1) * 32;      // K staging d-half
  const int vrow = tid >> 2;           // V staging row (d) 0..63
  const int vcg  = (tid & 3) * 32;     // V staging col group
  const ushort* vgl = vt + ((size_t)bh * DHD + vrow) * SS + vcg;

  const int qg0 = qt * 64 + w * 16;    // wave's first q row

  for (int kt = 0; kt < 4; ++kt) {
    // ---- issue global loads for K (row-major) and V^T tiles ----
    const size_t gbase = ((size_t)(b * SS + kt * 128 + skr) * DD) + h * DHD + shd;
    int4 kr0 = *(const int4*)(kb + gbase);
    int4 kr1 = *(const int4*)(kb + gbase + 8);
    int4 kr2 = *(const int4*)(kb + gbase + 16);
    int4 kr3 = *(const int4*)(kb + gbase + 24);
    const ushort* vp = vgl + kt * 128;
    int4 vr0 = *(const int4*)(vp);
    int4 vr1 = *(const int4*)(vp + 8);
    int4 vr2 = *(const int4*)(vp + 16);
    int4 vr3 = *(const int4*)(vp + 24);

    __syncthreads();
    *(int4*)&Kt[skr][shd]      = kr0;
    *(int4*)&Kt[skr][shd + 8]  = kr1;
    *(int4*)&Kt[skr][shd + 16] = kr2;
    *(int4*)&Kt[skr][shd + 24] = kr3;
    *(int4*)&Vt[vrow][vcg]      = vr0;
    *(int4*)&Vt[vrow][vcg + 8]  = vr1;
    *(int4*)&Vt[vrow][vcg + 16] = vr2;
    *(int4*)&Vt[vrow][vcg + 24] = vr3;
    __syncthreads();

    // ---- QK^T + score epilogue (tables from LDS) ----
    float sv[8][4];
    __builtin_amdgcn_s_setprio(1);
#pragma unroll
    for (int kc = 0; kc < 8; ++kc) {
      f32x4 s = f32x4{0.f, 0.f, 0.f, 0.f};
      bf16x8 kf0 = *(const bf16x8*)&Kt[kc * 16 + fr][fg * 8];
      bf16x8 kf1 = *(const bf16x8*)&Kt[kc * 16 + fr][32 + fg * 8];
      s = __builtin_amdgcn_mfma_f32_16x16x32_bf16(qf[0], kf0, s, 0, 0, 0);
      s = __builtin_amdgcn_mfma_f32_16x16x32_bf16(qf[1], kf1, s, 0, 0, 0);
      const int col = kt * 128 + kc * 16 + fr;
      const float am = am_lds[col];
      const int ridx = col - qg0 - fg * 4 + 512;
#pragma unroll
      for (int r = 0; r < 4; ++r)
        sv[kc][r] = s[r] * 0.125f + rel_lds[ridx - r] + am;
    }
    __builtin_amdgcn_s_setprio(0);

    // ---- online softmax ----
    float ef[4];
#pragma unroll
    for (int r = 0; r < 4; ++r) {
      float tmax = sv[0][r];
#pragma unroll
      for (int kc = 1; kc < 8; ++kc) tmax = fmaxf(tmax, sv[kc][r]);
#pragma unroll
      for (int off = 1; off < 16; off <<= 1) tmax = fmaxf(tmax, __shfl_xor(tmax, off));
      const float mnew = fmaxf(mrow[r], tmax);
      ef[r] = __expf(mrow[r] - mnew);
      float psum = 0.f;
      const int prow = w * 16 + fg * 4 + r;
#pragma unroll
      for (int kc = 0; kc < 8; ++kc) {
        float p = __expf(sv[kc][r] - mnew);
        psum += p;
        Pl[prow][kc * 16 + fr] = f2bf(p);
      }
#pragma unroll
      for (int off = 1; off < 16; off <<= 1) psum += __shfl_xor(psum, off);
      lrow[r] = lrow[r] * ef[r] + psum;
      mrow[r] = mnew;
    }
#pragma unroll
    for (int dc = 0; dc < 4; ++dc)
#pragma unroll
      for (int r = 0; r < 4; ++r) o[dc][r] *= ef[r];
    __syncthreads();

    // ---- PV ----
    __builtin_amdgcn_s_setprio(1);
#pragma unroll
    for (int dc = 0; dc < 4; ++dc)
#pragma unroll
      for (int ks = 0; ks < 4; ++ks) {
        bf16x8 pf = *(const bf16x8*)&Pl[w * 16 + fr][ks * 32 + fg * 8];
        bf16x8 vf = *(const bf16x8*)&Vt[dc * 16 + fr][ks * 32 + fg * 8];
        o[dc] = __builtin_amdgcn_mfma_f32_16x16x32_bf16(pf, vf, o[dc], 0, 0, 0);
      }
    __builtin_amdgcn_s_setprio(0);
  }

#pragma unroll
  for (int dc = 0; dc < 4; ++dc)
#pragma unroll
    for (int r = 0; r < 4; ++r) {
      const int qg = qt * 64 + w * 16 + fg * 4 + r;
      const float v = o[dc][r] / lrow[r];
      ctxb[((size_t)(b * SS + qg) * DD) + h * DHD + dc * 16 + fr] = f2bf(v);
    }
}

// ================= host launch =================
extern "C" void kernel_launch(void* const* d_in, const int* in_sizes, int n_in,
                              void* d_out, int out_size, void* d_ws, size_t ws_size,
                              hipStream_t stream) {
  const int*   ids   = (const int*)d_in[0];
  const float* amask = (const float*)d_in[1];
  const float* wemb  = (const float*)d_in[2];
  const float* pemb  = (const float*)d_in[3];
  const float* eln_w = (const float*)d_in[4];
  const float* eln_b = (const float*)d_in[5];
  const float* relt  = (const float*)d_in[6];
  const float* Wq    = (const float*)d_in[7];
  const float* bq    = (const float*)d_in[8];
  const float* Wk    = (const float*)d_in[9];
  const float* bk    = (const float*)d_in[10];
  const float* Wv    = (const float*)d_in[11];
  const float* bv    = (const float*)d_in[12];
  const float* Wo    = (const float*)d_in[13];
  const float* bo    = (const float*)d_in[14];
  const float* aln_w = (const float*)d_in[15];
  const float* aln_b = (const float*)d_in[16];
  const float* Wi    = (const float*)d_in[17];
  const float* bi    = (const float*)d_in[18];
  const float* Wd    = (const float*)d_in[19];
  const float* bd    = (const float*)d_in[20];
  const float* oln_w = (const float*)d_in[21];
  const float* oln_b = (const float*)d_in[22];

  size_t off = 0;
  auto carve = [&](size_t bytes) -> void* {
    void* r = (char*)d_ws + off;
    off += (bytes + 255) & ~(size_t)255;
    return r;
  };
  float*  hf     = (float*) carve((size_t)MM * DD * 4);
  ushort* hb     = (ushort*)carve((size_t)MM * DD * 2);
  ushort* qbuf   = (ushort*)carve((size_t)MM * DD * 2);
  ushort* kbuf   = (ushort*)carve((size_t)MM * DD * 2);
  ushort* vbuf   = (ushort*)carve((size_t)MM * DD * 2);   // holds vT[b][h][d][s]
  ushort* ctxb   = (ushort*)carve((size_t)MM * DD * 2);
  float*  gout   = (float*) carve((size_t)MM * DD * 4);
  ushort* interb = (ushort*)carve((size_t)MM * FF * 2);

  ushort* wA = interb;   // Wq,Wk,Wv,Wo bf16 in interb's dead window
  ushort* wB = qbuf;     // Wi,Wd bf16 in qbuf's dead window (after attn)
  const int PD = DD * DD;
  const int PF = FF * DD;

  embed_ln_kernel<<<MM, 256, 0, stream>>>(ids, wemb, pemb, eln_w, eln_b, hf, hb);

  const dim3 gQKV(MM / 128, 3 * (DD / 128));  // 64 x 18
  const dim3 gD(MM / 128, DD / 128);          // 64 x 6
  const dim3 gF(MM / 128, FF / 128);          // 64 x 24
  const dim3 gA(SS / 64, BB * HH);            // 8 x 192
  const dim3 gCA(PD / 1024, 4);
  const dim3 gCB(PF / 1024, 2);

  for (int l = 0; l < LL; ++l) {
    const size_t wo  = (size_t)l * PD;
    const size_t wio = (size_t)l * PF;

    convw4<<<gCA, 256, 0, stream>>>(Wq + wo, Wk + wo, Wv + wo, Wo + wo, wA, PD);

    gemm_ker<0, true><<<gQKV, 256, 0, stream>>>(hb, wA, wA + PD, wA + 2 * PD,
                                                bq + l * DD, bk + l * DD, bv + l * DD,
                                                qbuf, kbuf, vbuf, DD, DD / 128);

    attn_kernel<<<gA, 256, 0, stream>>>(qbuf, kbuf, vbuf, relt, amask, ctxb);

    convw4<<<gCB, 256, 0, stream>>>(Wi + wio, Wd + wio, Wi + wio, Wi + wio, wB, PF);

    gemm_ker<1, false><<<gD, 256, 0, stream>>>(ctxb, wA + 3 * PD, wA + 3 * PD, wA + 3 * PD,
                                               bo + l * DD, bo + l * DD, bo + l * DD,
                                               gout, gout, gout, DD, DD / 128);
    add_ln_kernel<<<MM, 256, 0, stream>>>(hf, gout, aln_w + l * DD, aln_b + l * DD, hf, hb);

    gemm_ker<2, false><<<gF, 256, 0, stream>>>(hb, wB, wB, wB,
                                               bi + l * FF, bi + l * FF, bi + l * FF,
                                               interb, interb, interb, DD, FF / 128);
    gemm_ker<1, false><<<gD, 256, 0, stream>>>(interb, wB + PF, wB + PF, wB + PF,
                                               bd + l * DD, bd + l * DD, bd + l * DD,
                                               gout, gout, gout, FF, DD / 128);

    float* outp = (l == LL - 1) ? (float*)d_out : hf;
    add_ln_kernel<<<MM, 256, 0, stream>>>(hf, gout, oln_w + l * DD, oln_b + l * DD, outp, hb);
  }
}